// Round 6
// baseline (205.517 us; speedup 1.0000x reference)
//
#include <hip/hip_runtime.h>

// entmax-1.5 over last axis of (1024, 255, 512) fp32.
// tau solve: fused(shift + Michelot quadratic @ tau=-1) + 4 Newton.
// Layout: 16 lanes/row, 4 rows/wave, 32 elems/lane as v2f (packed fp32).
// R6: register-lean so __launch_bounds__(256,8) is met WITHOUT spilling:
// loads land raw in x2, one fused scale/shift/Michelot pass, 3 packed temps.

typedef float v2f __attribute__((ext_vector_type(2)));
typedef float v4f __attribute__((ext_vector_type(4)));

constexpr int N_FEAT = 512;
constexpr long long N_ROWS = 1024LL * 255LL;   // 261120
constexpr int ROWS_PER_BLOCK = 16;             // 256 threads = 4 waves x 4 rows
constexpr float TAU_HI = -0.044194174f;        // -1/sqrt(512) >= tau* always

template <int CTRL>
__device__ __forceinline__ float dpp_add(float v) {
    int p = __builtin_amdgcn_update_dpp(0, __float_as_int(v), CTRL, 0xF, 0xF, true);
    return v + __int_as_float(p);
}
template <int CTRL>
__device__ __forceinline__ float dpp_max(float v) {
    int p = __builtin_amdgcn_update_dpp(0, __float_as_int(v), CTRL, 0xF, 0xF, true);
    return fmaxf(v, __int_as_float(p));
}
__device__ __forceinline__ float reduce16_add(float v) {
    v = dpp_add<0xB1>(v);   // quad_perm xor1
    v = dpp_add<0x4E>(v);   // quad_perm xor2
    v = dpp_add<0x141>(v);  // row_half_mirror
    v = dpp_add<0x140>(v);  // row_mirror
    return v;
}
__device__ __forceinline__ float reduce16_max(float v) {
    v = dpp_max<0xB1>(v);
    v = dpp_max<0x4E>(v);
    v = dpp_max<0x141>(v);
    v = dpp_max<0x140>(v);
    return v;
}

__global__ __launch_bounds__(256, 8) void entmax15_kernel(const float* __restrict__ in,
                                                          float* __restrict__ out) {
    const int wave = threadIdx.x >> 6;
    const int lane = threadIdx.x & 63;
    const int g    = lane >> 4;   // row within wave (0..3)
    const int t    = lane & 15;   // lane within 16-lane row group

    const long long row = (long long)blockIdx.x * ROWS_PER_BLOCK + wave * 4 + g;
    const float* rp = in  + row * N_FEAT + t * 4;
    float*       op = out + row * N_FEAT + t * 4;

    // Raw values straight into x2 (no staging, no scale pass).
    v2f x2[16];
#pragma unroll
    for (int k = 0; k < 8; ++k) {
        v4f v = *reinterpret_cast<const v4f*>(rp + k * 64);
        x2[2 * k]     = (v2f){v.x, v.y};
        x2[2 * k + 1] = (v2f){v.z, v.w};
    }

    // max of raw logits (packed tree + 16-lane DPP reduce), then halve.
    v2f mm = x2[0];
#pragma unroll
    for (int k = 1; k < 16; ++k) mm = __builtin_elementwise_max(mm, x2[k]);
    const float m = reduce16_max(fmaxf(mm.x, mm.y)) * 0.5f;

    const v2f zero2 = {0.0f, 0.0f};
    const v2f one2  = {1.0f, 1.0f};

    // Fused pass: x = raw*0.5 - m (stored), plus Michelot stats at tau = -1:
    // d = relu(x+1), s1 += d, s2 += d^2, cnt += indicator(d>0) via min(d*1e12,1).
    v2f s1v = zero2, s2v = zero2, cv = zero2;
#pragma unroll
    for (int k = 0; k < 16; ++k) {
        v2f x = x2[k] * 0.5f - m;
        x2[k] = x;
        v2f d = __builtin_elementwise_max(x + one2, zero2);
        s1v += d;
        s2v += d * d;
        cv  += __builtin_elementwise_min(d * 1e12f, one2);
    }
    float s1 = reduce16_add(s1v.x + s1v.y);
    float s2 = reduce16_add(s2v.x + s2v.y);
    float kk = reduce16_add(cv.x + cv.y);
    // |A| d^2 - 2 s1 d + (s2-1) = 0, smaller root; s2 >= 1 (max elem gives 1).
    float disc = fmaxf(fmaf(s1, s1, -kk * (s2 - 1.0f)), 0.0f);
    float tau = -1.0f + (s1 - __builtin_amdgcn_sqrtf(disc)) * __builtin_amdgcn_rcpf(kk);
    tau = fminf(fmaxf(tau, -1.0f), TAU_HI);

    // Newton polish: f(tau) = sum relu(x-tau)^2 = 1. Clamp keeps S1 >= 0.044.
#pragma unroll
    for (int it = 0; it < 4; ++it) {
        v2f t2 = {tau, tau};
        v2f a = zero2, b = zero2;
#pragma unroll
        for (int k = 0; k < 16; ++k) {
            v2f d = __builtin_elementwise_max(x2[k] - t2, zero2);
            a += d;
            b += d * d;
        }
        float S1 = reduce16_add(a.x + a.y);
        float S2 = reduce16_add(b.x + b.y);
        tau += (S2 - 1.0f) * __builtin_amdgcn_rcpf(2.0f * S1);
        tau = fminf(fmaxf(tau, -1.0f), TAU_HI);
    }

    // out = relu(x - tau)^2, nontemporal stores (output never re-read).
    v2f t2 = {tau, tau};
#pragma unroll
    for (int k = 0; k < 8; ++k) {
        v2f d0 = __builtin_elementwise_max(x2[2 * k]     - t2, zero2);
        v2f d1 = __builtin_elementwise_max(x2[2 * k + 1] - t2, zero2);
        d0 *= d0;
        d1 *= d1;
        v4f o = {d0.x, d0.y, d1.x, d1.y};
        __builtin_nontemporal_store(o, reinterpret_cast<v4f*>(op + k * 64));
    }
}

extern "C" void kernel_launch(void* const* d_in, const int* in_sizes, int n_in,
                              void* d_out, int out_size, void* d_ws, size_t ws_size,
                              hipStream_t stream) {
    const float* in  = (const float*)d_in[0];
    float*       out = (float*)d_out;
    const unsigned nblocks = (unsigned)(N_ROWS / ROWS_PER_BLOCK);  // 16320
    entmax15_kernel<<<dim3(nblocks), dim3(256), 0, stream>>>(in, out);
}